// Round 1
// baseline (411.443 us; speedup 1.0000x reference)
//
#include <hip/hip_runtime.h>

#define HID 512
#define HP  513
#define BB  128
#define OD  256
#define KD  263169   /* 513*513 */
#define MR  160      /* 128 data rows + gamma(128) + beta(129) + zero pad to 160 */
#define BKK 64
#define EPSV 1e-5f

typedef float f32x4 __attribute__((ext_vector_type(4)));
typedef short s16x8 __attribute__((ext_vector_type(8)));

static __device__ __forceinline__ unsigned short f2bf(float f) {
    union { float f; unsigned u; } x; x.f = f;
    unsigned r = x.u + 0x7FFFu + ((x.u >> 16) & 1u);   // RNE
    return (unsigned short)(r >> 16);
}

// ---------------- prep: transpose a,v into [HP][BB] with leading ones row ----
__global__ void prep_transpose(const float* __restrict__ a, const float* __restrict__ v,
                               float* __restrict__ at, float* __restrict__ vt) {
    int m = blockIdx.x, t = threadIdx.x;
    if (t == 0) { at[m] = 1.f; vt[m] = 1.f; }
    for (int h = t; h < HID; h += 256) {
        at[(1 + h) * BB + m] = a[m * HID + h];
        vt[(1 + h) * BB + m] = v[m * HID + h];
    }
}

// ---------------- stats: mu, rsig per row (rank-1 separable LN) --------------
__global__ void stats_kernel(const float* __restrict__ a, const float* __restrict__ v,
                             float* __restrict__ mu, float* __restrict__ rsig) {
    __shared__ float s1[256], s2[256], s3[256], s4[256];
    int m = blockIdx.x, t = threadIdx.x;
    float a0 = a[m * HID + t], a1 = a[m * HID + t + 256];
    float v0 = v[m * HID + t], v1 = v[m * HID + t + 256];
    s1[t] = a0 + a1; s2[t] = a0 * a0 + a1 * a1;
    s3[t] = v0 + v1; s4[t] = v0 * v0 + v1 * v1;
    __syncthreads();
    for (int off = 128; off > 0; off >>= 1) {
        if (t < off) { s1[t] += s1[t + off]; s2[t] += s2[t + off];
                       s3[t] += s3[t + off]; s4[t] += s4[t + off]; }
        __syncthreads();
    }
    if (t == 0) {
        float Sa = 1.f + s1[0], Qa = 1.f + s2[0];
        float Sv = 1.f + s3[0], Qv = 1.f + s4[0];
        float muv = Sa * Sv / (float)KD;
        float var = Qa * Qv / (float)KD - muv * muv;
        mu[m]   = muv;
        rsig[m] = rsqrtf(var + EPSV);
    }
}

// ---------------- main: split-K MFMA GEMM, A generated on the fly ------------
// A[m][d] = ah[m,i]*vh[m,j]*gamma[d] (m<128), row128=gamma, row129=beta, rest 0
// P_partial[chunk][m][o] = sum_{d in chunk} A[m][d] * W[o][d]
__global__ __launch_bounds__(256) void gemm_partial(
        const float* __restrict__ at, const float* __restrict__ vt,
        const float* __restrict__ gamma, const float* __restrict__ beta,
        const float* __restrict__ W, float* __restrict__ part, int KC) {
    __shared__ __align__(16) unsigned short As[MR][72];   // +8 pad per row
    __shared__ __align__(16) unsigned short Ws[64][72];

    const int tid   = threadIdx.x;
    const int o0    = blockIdx.x * 64;
    const int kbase = blockIdx.y * KC;
    const int kend  = (kbase + KC < KD) ? (kbase + KC) : KD;

    // zero rows 130..159 once (30 rows x 8 groups of 8 ushorts)
    for (int idx = tid; idx < 30 * 8; idx += 256) {
        int r = 130 + (idx >> 3), c = (idx & 7) * 8;
        *(uint4*)&As[r][c] = make_uint4(0u, 0u, 0u, 0u);
    }

    const int w    = tid >> 6, lane = tid & 63;
    const int wm   = w >> 1,   wn   = w & 1;      // 2x2 wave grid
    const int mrow0 = wm * 80;                    // 5 M-tiles per wave
    const int lr = lane & 15, lg = lane >> 4;

    f32x4 acc[5][2];
#pragma unroll
    for (int i = 0; i < 5; ++i)
#pragma unroll
        for (int j = 0; j < 2; ++j)
            acc[i][j] = {0.f, 0.f, 0.f, 0.f};

    const int sm  = tid & 127;            // A-stage row
    const int skh = (tid >> 7) * 32;      // A-stage k half

    for (int k0 = kbase; k0 < kend; k0 += BKK) {
        __syncthreads();
        // ---- stage W tile: Ws[n][k] = bf16(W[o0+n][k0+k]) (scalar: rows 4B-aligned)
#pragma unroll
        for (int q = 0; q < 16; ++q) {
            int flat = tid + 256 * q;          // 0..4095
            int n = flat >> 6, k = flat & 63;
            int d = k0 + k;
            float f = (d < KD) ? W[(size_t)(o0 + n) * KD + d] : 0.f;
            Ws[n][k] = f2bf(f);
        }
        // ---- stage A rows 0..127 (each thread: 32 k's for one m)
        {
            int icur = -1; float av = 0.f;
#pragma unroll
            for (int g = 0; g < 4; ++g) {
                unsigned bw[4];
#pragma unroll
                for (int p = 0; p < 4; ++p) {
                    float val2[2];
#pragma unroll
                    for (int e = 0; e < 2; ++e) {
                        int k = k0 + skh + g * 8 + p * 2 + e;
                        float val = 0.f;
                        if (k < KD) {
                            int i = (int)((unsigned)k / 513u);
                            int j = k - i * 513;
                            if (i != icur) { icur = i; av = at[i * BB + sm]; }
                            val = av * vt[j * BB + sm] * gamma[k];
                        }
                        val2[e] = val;
                    }
                    bw[p] = (unsigned)f2bf(val2[0]) | ((unsigned)f2bf(val2[1]) << 16);
                }
                *(uint4*)&As[sm][skh + g * 8] = make_uint4(bw[0], bw[1], bw[2], bw[3]);
            }
        }
        // ---- rows 128 (gamma) / 129 (beta)
        if (tid < 128) {
            int r = 128 + (tid >> 6), kk = tid & 63;
            int k = k0 + kk;
            float f = 0.f;
            if (k < KD) f = (r == 128) ? gamma[k] : beta[k];
            As[r][kk] = f2bf(f);
        }
        __syncthreads();
        // ---- MFMA compute: wave owns 5 M-tiles x 2 N-subtiles
#pragma unroll
        for (int ks = 0; ks < 2; ++ks) {
            s16x8 bfr[2];
#pragma unroll
            for (int nt = 0; nt < 2; ++nt)
                bfr[nt] = *(const s16x8*)&Ws[wn * 32 + nt * 16 + lr][ks * 32 + lg * 8];
#pragma unroll
            for (int mt = 0; mt < 5; ++mt) {
                s16x8 afr = *(const s16x8*)&As[mrow0 + mt * 16 + lr][ks * 32 + lg * 8];
#pragma unroll
                for (int nt = 0; nt < 2; ++nt)
                    acc[mt][nt] = __builtin_amdgcn_mfma_f32_16x16x32_bf16(
                        afr, bfr[nt], acc[mt][nt], 0, 0, 0);
            }
        }
    }

    // ---- write partials: part[blk.y][row][col]
    float* dst = part + (size_t)blockIdx.y * (MR * OD);
#pragma unroll
    for (int mt = 0; mt < 5; ++mt)
#pragma unroll
        for (int nt = 0; nt < 2; ++nt)
#pragma unroll
            for (int e = 0; e < 4; ++e) {
                int row = mrow0 + mt * 16 + lg * 4 + e;   // C/D: row=(lane>>4)*4+reg
                int col = o0 + wn * 32 + nt * 16 + lr;    //      col=lane&15
                dst[row * OD + col] = acc[mt][nt][e];
            }
}

// ---------------- reduce partials over K-chunks ------------------------------
__global__ void reduce_kernel(const float* __restrict__ part, float* __restrict__ Pred, int nk) {
    int r = blockIdx.x, o = threadIdx.x;
    float s = 0.f;
    for (int c = 0; c < nk; ++c) s += part[(size_t)c * (MR * OD) + r * OD + o];
    Pred[r * OD + o] = s;
}

// ---------------- finalize: LN fold + bias + relu ----------------------------
__global__ void finalize_kernel(const float* __restrict__ Pred, const float* __restrict__ mu,
                                const float* __restrict__ rsig, const float* __restrict__ bias,
                                float* __restrict__ out) {
    int b = blockIdx.x, o = threadIdx.x;
    float P  = Pred[b * OD + o];
    float Sg = Pred[128 * OD + o];
    float Sb = Pred[129 * OD + o];
    float x = rsig[b] * (P - mu[b] * Sg) + Sb + bias[o];
    out[b * OD + o] = fmaxf(x, 0.f);
}

extern "C" void kernel_launch(void* const* d_in, const int* in_sizes, int n_in,
                              void* d_out, int out_size, void* d_ws, size_t ws_size,
                              hipStream_t stream) {
    const float* a     = (const float*)d_in[0];
    const float* v     = (const float*)d_in[1];
    const float* gamma = (const float*)d_in[2];
    const float* beta  = (const float*)d_in[3];
    const float* W     = (const float*)d_in[4];
    const float* bias  = (const float*)d_in[5];
    float* out = (float*)d_out;

    float* at   = (float*)d_ws;          // HP*BB
    float* vt   = at + HP * BB;          // HP*BB
    float* mu   = vt + HP * BB;          // BB
    float* rsig = mu + BB;               // BB
    float* Pred = rsig + BB;             // MR*OD
    float* part = Pred + MR * OD;        // NK * MR*OD

    size_t fixedB = (size_t)(2 * HP * BB + 2 * BB + MR * OD) * sizeof(float);
    size_t sliceB = (size_t)MR * OD * sizeof(float);
    int NK = 1;
    if (ws_size > fixedB + sliceB) {
        size_t q = (ws_size - fixedB) / sliceB;
        NK = (q < 128) ? (int)q : 128;
        if (NK < 1) NK = 1;
    }
    int KC = (KD + NK - 1) / NK;
    KC = ((KC + BKK - 1) / BKK) * BKK;
    int NKeff = (KD + KC - 1) / KC;

    prep_transpose<<<BB, 256, 0, stream>>>(a, v, at, vt);
    stats_kernel<<<BB, 256, 0, stream>>>(a, v, mu, rsig);
    gemm_partial<<<dim3(4, NKeff), 256, 0, stream>>>(at, vt, gamma, beta, W, part, KC);
    reduce_kernel<<<MR, 256, 0, stream>>>(part, Pred, NKeff);
    finalize_kernel<<<BB, 256, 0, stream>>>(Pred, mu, rsig, bias, out);
}

// Round 2
// 161.950 us; speedup vs baseline: 2.5406x; 2.5406x over previous
//
#include <hip/hip_runtime.h>

#define HID 512
#define BB  128
#define OD  256
#define HP  513
#define KD  263169          /* 513*513 */
#define MT  128             /* stage1 M-tile rows */
#define NB  1026            /* 131328 / MT */
#define NCOL 144            /* 128 m + col128=ones + pad */
#define KP  576             /* padded K (9*64) */
#define EPSV 1e-5f

typedef float f32x4 __attribute__((ext_vector_type(4)));
typedef short s16x8 __attribute__((ext_vector_type(8)));

static __device__ __forceinline__ unsigned short f2bf(float f) {
    union { float f; unsigned u; } x; x.f = f;
    unsigned r = x.u + 0x7FFFu + ((x.u >> 16) & 1u);   // RNE
    return (unsigned short)(r >> 16);
}

// ---------- prep: gb interleave, vhT (bf16, transposed, padded), ahT --------
__global__ void prep_all(const float* __restrict__ a, const float* __restrict__ v,
                         const float* __restrict__ gamma, const float* __restrict__ beta,
                         float* __restrict__ gb, unsigned short* __restrict__ vhT,
                         float* __restrict__ ahT) {
    int b = blockIdx.x, t = threadIdx.x;
    if (b < 1029) {
        int d = b * 256 + t;
        if (d < KD) {
            float2 g; g.x = gamma[d]; g.y = beta[d];
            *(float2*)(gb + 2 * (size_t)d) = g;
        }
    } else if (b < 1029 + NCOL) {
        int n = b - 1029;
        for (int j = t; j < KP; j += 256) {
            float val = 0.f;
            if (n < 128)       val = (j == 0) ? 1.f : (j <= 512 ? v[n * HID + j - 1] : 0.f);
            else if (n == 128) val = (j < HP) ? 1.f : 0.f;
            vhT[n * KP + j] = f2bf(val);
        }
    } else {
        int idx = (b - 1029 - NCOL) * 256 + t;
        if (idx < HP * 128) {
            int i = idx >> 7, m = idx & 127;
            ahT[idx] = (i == 0) ? 1.f : a[m * HID + i - 1];
        }
    }
}

// ---------- stats: mu, rsig per row (rank-1 separable LN) -------------------
__global__ void stats_kernel(const float* __restrict__ a, const float* __restrict__ v,
                             float* __restrict__ mu, float* __restrict__ rsig) {
    __shared__ float s1[256], s2[256], s3[256], s4[256];
    int m = blockIdx.x, t = threadIdx.x;
    float a0 = a[m * HID + t], a1 = a[m * HID + t + 256];
    float v0 = v[m * HID + t], v1 = v[m * HID + t + 256];
    s1[t] = a0 + a1; s2[t] = a0 * a0 + a1 * a1;
    s3[t] = v0 + v1; s4[t] = v0 * v0 + v1 * v1;
    __syncthreads();
    for (int off = 128; off > 0; off >>= 1) {
        if (t < off) { s1[t] += s1[t + off]; s2[t] += s2[t + off];
                       s3[t] += s3[t + off]; s4[t] += s4[t + off]; }
        __syncthreads();
    }
    if (t == 0) {
        float Sa = 1.f + s1[0], Qa = 1.f + s2[0];
        float Sv = 1.f + s3[0], Qv = 1.f + s4[0];
        float muv = Sa * Sv / (float)KD;
        float var = Qa * Qv / (float)KD - muv * muv;
        mu[m]   = muv;
        rsig[m] = rsqrtf(var + EPSV);
    }
}

// ---------- stage1: stream W as A-operand, stationary vhT as B --------------
// A row oi = gamma-scaled W[o][i*513 .. +513]; acc = T[oi][m]; epilogue folds
// ah-weighted i-reduction -> Pblk[b][slot][144]; beta*W side-sum -> SbPart.
__global__ __launch_bounds__(256) void stage1(
        const float* __restrict__ W, const float* __restrict__ gb,
        const unsigned short* __restrict__ vhT, const float* __restrict__ ahT,
        float* __restrict__ Pblk, float* __restrict__ SbPart) {
    __shared__ __align__(16) unsigned short As[MT][72];
    __shared__ __align__(16) unsigned short Bs[NCOL][72];
    __shared__ unsigned c_lds[MT];
    __shared__ float red[2][9][16][4];
    __shared__ float sbred[2][4];

    const int b = blockIdx.x, tid = threadIdx.x;
    const int lane = tid & 63, w = tid >> 6;
    const int lr = lane & 15, lg = lane >> 4;
    const unsigned oi0 = (unsigned)b * MT;
    const unsigned ofirst = oi0 / (unsigned)HP;
    const unsigned osw = (ofirst + 1) * (unsigned)HP;

    if (tid < MT) {
        unsigned oi = oi0 + tid;
        c_lds[tid] = (oi * (unsigned)HP) % (unsigned)KD;
    }

    f32x4 acc[2][9];
#pragma unroll
    for (int mt = 0; mt < 2; ++mt)
#pragma unroll
        for (int nt = 0; nt < 9; ++nt) acc[mt][nt] = {0.f, 0.f, 0.f, 0.f};

    float sb0 = 0.f, sb1 = 0.f;
    __syncthreads();

    for (int k0 = 0; k0 < KP; k0 += 64) {
        const int j = k0 + lane;
        const bool jv = (j < HP);
        // ---- A tile: wave w stages rows w*32..+31, lane = k (coalesced)
#pragma unroll 4
        for (int rr = 0; rr < 32; ++rr) {
            int r = w * 32 + rr;
            unsigned oi = oi0 + (unsigned)r;
            float wv = 0.f, gv = 0.f, bv = 0.f;
            if (jv) {
                wv = W[(size_t)oi * HP + j];
                unsigned d = c_lds[r] + (unsigned)j;
                if (d >= (unsigned)KD) d -= (unsigned)KD;
                float2 g2 = *(const float2*)(gb + 2 * (size_t)d);
                gv = g2.x; bv = g2.y;
            }
            float prod = bv * wv;
            if (oi >= osw) sb1 += prod; else sb0 += prod;
            As[r][lane] = f2bf(gv * wv);
        }
        // ---- B tile: Bs[n][0..63] <- vhT[n][k0..+64] (16B both sides)
        for (int idx = tid; idx < NCOL * 8; idx += 256) {
            int n = idx >> 3, kk = (idx & 7) * 8;
            *(uint4*)&Bs[n][kk] = *(const uint4*)&vhT[n * KP + k0 + kk];
        }
        __syncthreads();
        // ---- MFMA
#pragma unroll
        for (int ks = 0; ks < 2; ++ks) {
            s16x8 bfr[9];
#pragma unroll
            for (int nt = 0; nt < 9; ++nt)
                bfr[nt] = *(const s16x8*)&Bs[nt * 16 + lr][ks * 32 + lg * 8];
#pragma unroll
            for (int mt = 0; mt < 2; ++mt) {
                s16x8 afr = *(const s16x8*)&As[w * 32 + mt * 16 + lr][ks * 32 + lg * 8];
#pragma unroll
                for (int nt = 0; nt < 9; ++nt)
                    acc[mt][nt] = __builtin_amdgcn_mfma_f32_16x16x32_bf16(
                        afr, bfr[nt], acc[mt][nt], 0, 0, 0);
            }
        }
        __syncthreads();
    }

    // ---- epilogue: P[m] += ah[m,i] * T[oi][m], slot-split by o -------------
    float psum[2][9];
#pragma unroll
    for (int s = 0; s < 2; ++s)
#pragma unroll
        for (int nt = 0; nt < 9; ++nt) psum[s][nt] = 0.f;

#pragma unroll
    for (int mt = 0; mt < 2; ++mt) {
        unsigned oibase = oi0 + (unsigned)(w * 32 + mt * 16 + lg * 4);
#pragma unroll
        for (int e = 0; e < 4; ++e) {
            unsigned oi = oibase + (unsigned)e;
            int s = (oi >= osw) ? 1 : 0;
            unsigned i = oi - (s ? osw : ofirst * (unsigned)HP);
            const float* ahrow = ahT + (size_t)i * 128;
#pragma unroll
            for (int nt = 0; nt < 9; ++nt) {
                float wgt = (nt < 8) ? ahrow[nt * 16 + lr] : 1.f;
                psum[s][nt] = fmaf(acc[mt][nt][e], wgt, psum[s][nt]);
            }
        }
    }
#pragma unroll
    for (int s = 0; s < 2; ++s)
#pragma unroll
        for (int nt = 0; nt < 9; ++nt) {
            float r = psum[s][nt];
            r += __shfl_xor(r, 16);
            r += __shfl_xor(r, 32);
            psum[s][nt] = r;
        }
    if (lane < 16) {
#pragma unroll
        for (int s = 0; s < 2; ++s)
#pragma unroll
            for (int nt = 0; nt < 9; ++nt) red[s][nt][lr][w] = psum[s][nt];
    }
    // beta side-sum: wave reduce then LDS
    float t0 = sb0, t1 = sb1;
#pragma unroll
    for (int off = 1; off < 64; off <<= 1) {
        t0 += __shfl_xor(t0, off);
        t1 += __shfl_xor(t1, off);
    }
    if (lane == 0) { sbred[0][w] = t0; sbred[1][w] = t1; }
    __syncthreads();
    for (int idx = tid; idx < 288; idx += 256) {
        int s = idx / 144, c = idx - s * 144;
        int nt = c >> 4, l2 = c & 15;
        float val = red[s][nt][l2][0] + red[s][nt][l2][1] +
                    red[s][nt][l2][2] + red[s][nt][l2][3];
        Pblk[((size_t)b * 2 + s) * NCOL + c] = val;
    }
    if (tid < 2)
        SbPart[b * 2 + tid] = sbred[tid][0] + sbred[tid][1] + sbred[tid][2] + sbred[tid][3];
}

// ---------- finalize: gather block partials, LN fold, bias, relu ------------
__global__ void finalize_kernel(const float* __restrict__ Pblk, const float* __restrict__ SbPart,
                                const float* __restrict__ mu, const float* __restrict__ rsig,
                                const float* __restrict__ bias, float* __restrict__ out) {
    int o = blockIdx.x, m = threadIdx.x;   // 128 threads
    __shared__ float sSg, sSb;
    int b0 = (o * HP) >> 7;
    int b1 = (o * HP + HP - 1) >> 7;
    float P = 0.f, Sg = 0.f, Sb = 0.f;
    for (int b = b0; b <= b1; ++b) {
        unsigned of = ((unsigned)b * MT) / (unsigned)HP;
        int s = o - (int)of;
        if (s < 0 || s > 1) continue;
        const float* pb = Pblk + ((size_t)b * 2 + s) * NCOL;
        P += pb[m];
        if (m == 0) { Sg += pb[128]; Sb += SbPart[b * 2 + s]; }
    }
    if (m == 0) { sSg = Sg; sSb = Sb; }
    __syncthreads();
    float x = rsig[m] * (P - mu[m] * sSg) + sSb + bias[o];
    out[m * OD + o] = fmaxf(x, 0.f);
}

extern "C" void kernel_launch(void* const* d_in, const int* in_sizes, int n_in,
                              void* d_out, int out_size, void* d_ws, size_t ws_size,
                              hipStream_t stream) {
    const float* a     = (const float*)d_in[0];
    const float* v     = (const float*)d_in[1];
    const float* gamma = (const float*)d_in[2];
    const float* beta  = (const float*)d_in[3];
    const float* W     = (const float*)d_in[4];
    const float* bias  = (const float*)d_in[5];
    float* out = (float*)d_out;

    float* cur = (float*)d_ws;
    float* mu     = cur; cur += 128;
    float* rsig   = cur; cur += 128;
    float* SbPart = cur; cur += NB * 2;
    float* Pblk   = cur; cur += (size_t)NB * 2 * NCOL;
    float* ahT    = cur; cur += (size_t)HP * 128;
    float* gb     = cur; cur += (size_t)2 * KD;
    unsigned short* vhT = (unsigned short*)cur;   // NCOL*KP ushorts

    prep_all<<<1029 + NCOL + 257, 256, 0, stream>>>(a, v, gamma, beta, gb, vhT, ahT);
    stats_kernel<<<BB, 256, 0, stream>>>(a, v, mu, rsig);
    stage1<<<NB, 256, 0, stream>>>(W, gb, vhT, ahT, Pblk, SbPart);
    finalize_kernel<<<OD, 128, 0, stream>>>(Pblk, SbPart, mu, rsig, bias, out);
}